// Round 7
// baseline (2922.748 us; speedup 1.0000x reference)
//
#include <hip/hip_runtime.h>
#include <hip/hip_bf16.h>
#include <hip/hip_cooperative_groups.h>

namespace cg = cooperative_groups;

typedef unsigned short u16;
typedef unsigned int u32;

#define NU 8192
#define NI 4096
#define DE 64
#define ELL_U 80
#define ELL_I 112
#define EPSF 1e-7f
#define NTHR 256

__device__ __forceinline__ float b2f(__hip_bfloat16 x) { return __bfloat162float(x); }

struct KP {
    const void* Hp; const void* ue; const void* ie;
    const void* w0; const void* b0; const void* w1; const void* b1;
    void* out;
    int* flag; int* cnt_u; int* cnt_i;
    u16* idx_u; u16* idx_i;
    float* a_f; float* p_f; float* b_f; float* q_f;
    float* dv_u; float* de1u; float* de2u;
    float* dv_i; float* de1i; float* de2i;
    float* Xu; float* Xi; float* Xsu; float* Xsi;
    float* T1u; float* TAu; float* TBu;
    float* T1i; float* TAi; float* TBi;
};

// 8-wide ILP gather with index prefetch (one L2 round-trip per 8 elements).
// Overreads <=16B past a row's live indices; stays inside allocated ws arrays.
__device__ __forceinline__ float sp_row(const u16* __restrict__ ip, int n,
                                        const float* __restrict__ src, int lane) {
    float a0 = 0.f, a1 = 0.f, a2 = 0.f, a3 = 0.f;
    float a4 = 0.f, a5 = 0.f, a6 = 0.f, a7 = 0.f;
    int p = 0;
    if (n >= 8) {
        ushort4 cA = *(const ushort4*)(ip);
        ushort4 cB = *(const ushort4*)(ip + 4);
        while (p + 8 <= n) {
            float g0 = src[((size_t)cA.x << 6) + lane];
            float g1 = src[((size_t)cA.y << 6) + lane];
            float g2 = src[((size_t)cA.z << 6) + lane];
            float g3 = src[((size_t)cA.w << 6) + lane];
            float g4 = src[((size_t)cB.x << 6) + lane];
            float g5 = src[((size_t)cB.y << 6) + lane];
            float g6 = src[((size_t)cB.z << 6) + lane];
            float g7 = src[((size_t)cB.w << 6) + lane];
            p += 8;
            cA = *(const ushort4*)(ip + p);      // prefetch before consuming
            cB = *(const ushort4*)(ip + p + 4);
            a0 += g0; a1 += g1; a2 += g2; a3 += g3;
            a4 += g4; a5 += g5; a6 += g6; a7 += g7;
        }
    }
    if (p + 4 <= n) {
        ushort4 cc = *(const ushort4*)(ip + p);
        a0 += src[((size_t)cc.x << 6) + lane];
        a1 += src[((size_t)cc.y << 6) + lane];
        a2 += src[((size_t)cc.z << 6) + lane];
        a3 += src[((size_t)cc.w << 6) + lane];
        p += 4;
    }
    for (; p < n; p++) a4 += src[((size_t)ip[p] << 6) + lane];
    return ((a0 + a1) + (a2 + a3)) + ((a4 + a5) + (a6 + a7));
}

__device__ __forceinline__ float sv_row_f(const u16* ip, int n, const float* sv) {
    float a0 = 0.f, a1 = 0.f, a2 = 0.f, a3 = 0.f;
    int p = 0;
    for (; p + 4 <= n; p += 4) {
        ushort4 cc = *(const ushort4*)(ip + p);
        a0 += sv[cc.x]; a1 += sv[cc.y]; a2 += sv[cc.z]; a3 += sv[cc.w];
    }
    for (; p < n; p++) a0 += sv[ip[p]];
    return (a0 + a1) + (a2 + a3);
}

__device__ __forceinline__ float sv_row_i(const u16* ip, int n, const int* sv) {
    float a0 = 0.f, a1 = 0.f, a2 = 0.f, a3 = 0.f;
    int p = 0;
    for (; p + 4 <= n; p += 4) {
        ushort4 cc = *(const ushort4*)(ip + p);
        a0 += (float)sv[cc.x]; a1 += (float)sv[cc.y];
        a2 += (float)sv[cc.z]; a3 += (float)sv[cc.w];
    }
    for (; p < n; p++) a0 += (float)sv[ip[p]];
    return (a0 + a1) + (a2 + a3);
}

// ---------------- phases ----------------

__device__ __forceinline__ void ph_zero(const KP& P, int t, int stride) {
    for (int e = t; e < NU + NI + 1; e += stride) {
        if (e == 0) P.flag[0] = 0;
        else if (e <= NU) P.cnt_u[e - 1] = 0;
        else P.cnt_i[e - 1 - NU] = 0;
    }
}

// dtype probe: H entries are exactly 0.0/1.0. fp32 words 0x00000000/0x3F800000
// (low u16 always 0); bf16 pairs expose 0x3F80 in low u16 for even-col nnz.
__device__ __forceinline__ void ph_detect(const KP& P, int t, int stride) {
    for (int e = t; e < 131072; e += stride) {
        u32 w = ((const u32*)P.Hp)[e];
        if ((w & 0xFFFFu) == 0x3F80u) P.flag[0] = 1;  // benign same-value race
    }
}

__device__ __forceinline__ void ph_fill(const KP& P, int t, int stride, int bf) {
    for (int q = t; q < (NU * NI / 8); q += stride) {
        int flat = q << 3;
        int i = flat >> 12;    // user row
        int j0 = flat & 4095;  // col base
        u32 words[8];
        if (bf) {
            uint4 v = ((const uint4*)P.Hp)[q];
            u32 p4[4] = {v.x, v.y, v.z, v.w};
#pragma unroll
            for (int k = 0; k < 4; k++) {
                words[2 * k] = p4[k] & 0xFFFFu;
                words[2 * k + 1] = p4[k] >> 16;
            }
        } else {
            uint4 a = ((const uint4*)P.Hp)[2 * q];
            uint4 b = ((const uint4*)P.Hp)[2 * q + 1];
            words[0] = a.x; words[1] = a.y; words[2] = a.z; words[3] = a.w;
            words[4] = b.x; words[5] = b.y; words[6] = b.z; words[7] = b.w;
        }
#pragma unroll
        for (int e = 0; e < 8; e++) {
            if (words[e]) {
                int j = j0 + e;
                int pu = atomicAdd(&P.cnt_u[i], 1);
                if (pu < ELL_U) P.idx_u[i * ELL_U + pu] = (u16)j;
                int pi = atomicAdd(&P.cnt_i[j], 1);
                if (pi < ELL_I) P.idx_i[j * ELL_I + pi] = (u16)i;
            }
        }
    }
}

__device__ __forceinline__ void ph_spmv1(const KP& P, int t, int stride) {
    for (int r = t; r < NI + NU; r += stride) {
        if (r < NI) {
            int n = min(P.cnt_i[r], ELL_I);
            P.a_f[r] = sv_row_i(P.idx_i + (size_t)r * ELL_I, n, P.cnt_u);
        } else {
            int u = r - NI;
            int n = min(P.cnt_u[u], ELL_U);
            P.p_f[u] = sv_row_i(P.idx_u + (size_t)u * ELL_U, n, P.cnt_i);
        }
    }
}

__device__ __forceinline__ void ph_spmv2(const KP& P, int t, int stride) {
    for (int r = t; r < NU + NI; r += stride) {
        if (r < NU) {
            int n = min(P.cnt_u[r], ELL_U);
            P.b_f[r] = sv_row_f(P.idx_u + (size_t)r * ELL_U, n, P.a_f);
        } else {
            int u = r - NU;
            int n = min(P.cnt_i[u], ELL_I);
            P.q_f[u] = sv_row_f(P.idx_i + (size_t)u * ELL_I, n, P.p_f);
        }
    }
}

__device__ __forceinline__ void ph_degx(const KP& P, int t, int stride, int bf) {
    for (int e = t; e < (NU + NI) * DE; e += stride) {
        if (e < NU) {
            float r = (float)P.cnt_u[e];
            P.dv_u[e] = 1.0f / sqrtf(r + P.b_f[e] + EPSF);
            P.de1i[e] = 1.0f / (r + EPSF);
            P.de2i[e] = 1.0f / (P.b_f[e] + EPSF);
        }
        if (e < NI) {
            float cd = (float)P.cnt_i[e];
            P.dv_i[e] = 1.0f / sqrtf(cd + P.q_f[e] + EPSF);
            P.de1u[e] = 1.0f / (cd + EPSF);
            P.de2u[e] = 1.0f / (P.q_f[e] + EPSF);
        }
        if (e < NU * DE) {
            int i = e >> 6, l = e & 63;
            float v = bf ? b2f(((const __hip_bfloat16*)P.ue)[e]) : ((const float*)P.ue)[e];
            P.Xu[e] = v;
            float dv = 1.0f / sqrtf((float)P.cnt_u[i] + P.b_f[i] + EPSF);
            P.Xsu[e] = dv * v;
            size_t o = (size_t)i * 192 + l;
            if (bf) ((__hip_bfloat16*)P.out)[o] = __float2bfloat16(v);
            else ((float*)P.out)[o] = v;
        } else {
            int s = e - NU * DE;
            int i = s >> 6, l = s & 63;
            float v = bf ? b2f(((const __hip_bfloat16*)P.ie)[s]) : ((const float*)P.ie)[s];
            P.Xi[s] = v;
            float dv = 1.0f / sqrtf((float)P.cnt_i[i] + P.q_f[i] + EPSF);
            P.Xsi[s] = dv * v;
            size_t o = (size_t)(NU + i) * 192 + l;
            if (bf) ((__hip_bfloat16*)P.out)[o] = __float2bfloat16(v);
            else ((float*)P.out)[o] = v;
        }
    }
}

// MODE 0: dst=acc ; 1: dst=ev[row]*acc ; 2: dst=acc+ev[row]*ax[o]
template <int MODE>
__device__ __forceinline__ void sp_stage(int gw, int nw, int lane,
    const int* cA, const u16* iA, int eA, int nA, const float* sA, float* dA,
    const float* vA, const float* xA,
    const int* cB, const u16* iB, int eB, int nB, const float* sB, float* dB,
    const float* vB, const float* xB) {
    for (int r = gw; r < nA + nB; r += nw) {
        bool isA = r < nA;
        const int* c = isA ? cA : cB;
        const u16* idx = isA ? iA : iB;
        int ell = isA ? eA : eB;
        const float* src = isA ? sA : sB;
        float* dst = isA ? dA : dB;
        int row = isA ? r : r - nA;
        int n = min(c[row], ell);
        float acc = sp_row(idx + (size_t)row * ell, n, src, lane);
        size_t o = ((size_t)row << 6) + lane;
        if (MODE == 0) {
            dst[o] = acc;
        } else if (MODE == 1) {
            const float* ev = isA ? vA : vB;
            dst[o] = ev[row] * acc;
        } else {
            const float* ev = isA ? vA : vB;
            const float* ax = isA ? xA : xB;
            dst[o] = acc + ev[row] * ax[o];
        }
    }
}

// final stage: M = dv*acc + X ; Xnext = M@w + b ; Xs = dv*Xnext ; emit out cols
__device__ __forceinline__ void sp_final(int gw, int nw, int lane, int bf,
    const int* cA, const u16* iA, int eA, int nA, const float* sA,
    const float* dvA, float* XA, float* XsA, size_t obA,
    const int* cB, const u16* iB, int eB, int nB, const float* sB,
    const float* dvB, float* XB, float* XsB, size_t obB,
    const void* w, const void* bias, void* out, int coloff) {
    for (int r = gw; r < nA + nB; r += nw) {
        bool isA = r < nA;
        const int* c = isA ? cA : cB;
        const u16* idx = isA ? iA : iB;
        int ell = isA ? eA : eB;
        const float* src = isA ? sA : sB;
        const float* dvv = isA ? dvA : dvB;
        float* X = isA ? XA : XB;
        float* Xs = isA ? XsA : XsB;
        size_t ob = isA ? obA : obB;
        int row = isA ? r : r - nA;
        int n = min(c[row], ell);
        float acc = sp_row(idx + (size_t)row * ell, n, src, lane);
        size_t o = ((size_t)row << 6) + lane;
        float dvr = dvv[row];
        float m = dvr * acc + X[o];
        float x0, x1 = 0.f, x2 = 0.f, x3 = 0.f;
        if (bf) {
            const __hip_bfloat16* __restrict__ wp = (const __hip_bfloat16*)w;
            x0 = b2f(((const __hip_bfloat16*)bias)[lane]);
            for (int k = 0; k < 64; k += 4) {
                x0 = fmaf(__shfl(m, k, 64), b2f(wp[(k << 6) + lane]), x0);
                x1 = fmaf(__shfl(m, k + 1, 64), b2f(wp[((k + 1) << 6) + lane]), x1);
                x2 = fmaf(__shfl(m, k + 2, 64), b2f(wp[((k + 2) << 6) + lane]), x2);
                x3 = fmaf(__shfl(m, k + 3, 64), b2f(wp[((k + 3) << 6) + lane]), x3);
            }
        } else {
            const float* __restrict__ wp = (const float*)w;
            x0 = ((const float*)bias)[lane];
            for (int k = 0; k < 64; k += 4) {
                x0 = fmaf(__shfl(m, k, 64), wp[(k << 6) + lane], x0);
                x1 = fmaf(__shfl(m, k + 1, 64), wp[((k + 1) << 6) + lane], x1);
                x2 = fmaf(__shfl(m, k + 2, 64), wp[((k + 2) << 6) + lane], x2);
                x3 = fmaf(__shfl(m, k + 3, 64), wp[((k + 3) << 6) + lane], x3);
            }
        }
        float xn = (x0 + x1) + (x2 + x3);
        X[o] = xn;
        Xs[o] = dvr * xn;
        size_t oo = ob + (size_t)row * 192 + coloff + lane;
        if (bf) ((__hip_bfloat16*)out)[oo] = __float2bfloat16(xn);
        else ((float*)out)[oo] = xn;
    }
}

__device__ __forceinline__ void ph_stage(const KP& P, int layer, int s,
                                         int gw, int nw, int lane, int bf) {
    switch (s) {
        case 0:  // T1 = A^T Xs (Xs = dv o X premultiplied)
            sp_stage<0>(gw, nw, lane,
                        P.cnt_i, P.idx_i, ELL_I, NI, P.Xsu, P.T1u, 0, 0,
                        P.cnt_u, P.idx_u, ELL_U, NU, P.Xsi, P.T1i, 0, 0);
            break;
        case 1:  // T2 = A T1
            sp_stage<0>(gw, nw, lane,
                        P.cnt_u, P.idx_u, ELL_U, NU, P.T1u, P.TAu, 0, 0,
                        P.cnt_i, P.idx_i, ELL_I, NI, P.T1i, P.TAi, 0, 0);
            break;
        case 2:  // T3 = de2 o (A^T T2)
            sp_stage<1>(gw, nw, lane,
                        P.cnt_i, P.idx_i, ELL_I, NI, P.TAu, P.TBu, P.de2u, 0,
                        P.cnt_u, P.idx_u, ELL_U, NU, P.TAi, P.TBi, P.de2i, 0);
            break;
        case 3:  // T4 = A T3
            sp_stage<0>(gw, nw, lane,
                        P.cnt_u, P.idx_u, ELL_U, NU, P.TBu, P.TAu, 0, 0,
                        P.cnt_i, P.idx_i, ELL_I, NI, P.TBi, P.TAi, 0, 0);
            break;
        case 4:  // S = A^T T4 + de1 o T1
            sp_stage<2>(gw, nw, lane,
                        P.cnt_i, P.idx_i, ELL_I, NI, P.TAu, P.TBu, P.de1u, P.T1u,
                        P.cnt_u, P.idx_u, ELL_U, NU, P.TAi, P.TBi, P.de1i, P.T1i);
            break;
        default: {  // s6: M = dv o (A S) + X ; Xnext = M w + b ; Xs = dv o Xnext
            const void* w = layer ? P.w1 : P.w0;
            const void* bb = layer ? P.b1 : P.b0;
            sp_final(gw, nw, lane, bf,
                     P.cnt_u, P.idx_u, ELL_U, NU, P.TBu, P.dv_u, P.Xu, P.Xsu, (size_t)0,
                     P.cnt_i, P.idx_i, ELL_I, NI, P.TBi, P.dv_i, P.Xi, P.Xsi,
                     (size_t)NU * 192,
                     w, bb, P.out, 64 + 64 * layer);
        } break;
    }
}

// phase < 0: run the full pipeline with grid.sync (cooperative launch).
// phase >= 0: run exactly one phase (ordinary launch; stream orders phases).
__global__ __launch_bounds__(NTHR, 2) void mega(KP P, int phase, int layer) {
    const int t = blockIdx.x * NTHR + threadIdx.x;
    const int stride = gridDim.x * NTHR;
    const int lane = threadIdx.x & 63;
    const int gw = t >> 6;
    const int nw = stride >> 6;
    if (phase < 0) {
        cg::grid_group g = cg::this_grid();
        ph_zero(P, t, stride);
        __threadfence(); g.sync(); __threadfence();
        ph_detect(P, t, stride);
        __threadfence(); g.sync(); __threadfence();
        int bf = P.flag[0];
        ph_fill(P, t, stride, bf);
        __threadfence(); g.sync(); __threadfence();
        ph_spmv1(P, t, stride);
        __threadfence(); g.sync(); __threadfence();
        ph_spmv2(P, t, stride);
        __threadfence(); g.sync(); __threadfence();
        ph_degx(P, t, stride, bf);
        __threadfence(); g.sync(); __threadfence();
        for (int L = 0; L < 2; L++) {
            for (int s = 0; s < 6; s++) {
                ph_stage(P, L, s, gw, nw, lane, bf);
                __threadfence(); g.sync(); __threadfence();
            }
        }
    } else {
        int bf = (phase >= 2) ? P.flag[0] : 0;
        switch (phase) {
            case 0: ph_zero(P, t, stride); break;
            case 1: ph_detect(P, t, stride); break;
            case 2: ph_fill(P, t, stride, bf); break;
            case 3: ph_spmv1(P, t, stride); break;
            case 4: ph_spmv2(P, t, stride); break;
            case 5: ph_degx(P, t, stride, bf); break;
            default: ph_stage(P, layer, phase - 6, gw, nw, lane, bf); break;
        }
    }
}

// ---------------- host ----------------

extern "C" void kernel_launch(void* const* d_in, const int* in_sizes, int n_in,
                              void* d_out, int out_size, void* d_ws, size_t ws_size,
                              hipStream_t stream) {
    char* ws = (char*)d_ws;
    size_t off = 0;
    auto alloc = [&](size_t bytes) -> char* {
        char* p = ws + off;
        off = (off + bytes + 255) & ~(size_t)255;
        return p;
    };

    KP P;
    P.Hp = d_in[0]; P.ue = d_in[1]; P.ie = d_in[2];
    P.w0 = d_in[3]; P.b0 = d_in[4]; P.w1 = d_in[5]; P.b1 = d_in[6];
    P.out = d_out;
    P.flag = (int*)alloc(256);
    P.cnt_u = (int*)alloc(NU * 4);
    P.cnt_i = (int*)alloc(NI * 4);
    P.idx_u = (u16*)alloc((size_t)NU * ELL_U * 2);
    P.idx_i = (u16*)alloc((size_t)NI * ELL_I * 2);
    P.a_f = (float*)alloc(NI * 4);
    P.p_f = (float*)alloc(NU * 4);
    P.b_f = (float*)alloc(NU * 4);
    P.q_f = (float*)alloc(NI * 4);
    P.dv_u = (float*)alloc(NU * 4);
    P.de1u = (float*)alloc(NI * 4);
    P.de2u = (float*)alloc(NI * 4);
    P.dv_i = (float*)alloc(NI * 4);
    P.de1i = (float*)alloc(NU * 4);
    P.de2i = (float*)alloc(NU * 4);
    P.Xu = (float*)alloc((size_t)NU * DE * 4);
    P.Xi = (float*)alloc((size_t)NI * DE * 4);
    P.Xsu = (float*)alloc((size_t)NU * DE * 4);
    P.Xsi = (float*)alloc((size_t)NI * DE * 4);
    P.T1u = (float*)alloc((size_t)NI * DE * 4);
    P.TAu = (float*)alloc((size_t)NU * DE * 4);
    P.TBu = (float*)alloc((size_t)NI * DE * 4);
    P.T1i = (float*)alloc((size_t)NU * DE * 4);
    P.TAi = (float*)alloc((size_t)NI * DE * 4);
    P.TBi = (float*)alloc((size_t)NU * DE * 4);
    (void)ws_size; (void)n_in; (void)in_sizes; (void)out_size;

    // Decide cooperative viability from host-only queries (capture-safe),
    // then verify the launch return code; fall back to 18 ordinary launches.
    bool done = false;
    int dev = 0;
    hipGetDevice(&dev);
    int coop = 0;
    hipDeviceGetAttribute(&coop, hipDeviceAttributeCooperativeLaunch, dev);
    if (coop) {
        int ncu = 0;
        hipDeviceGetAttribute(&ncu, hipDeviceAttributeMultiprocessorCount, dev);
        int maxb = 0;
        hipError_t oe = hipOccupancyMaxActiveBlocksPerMultiprocessor(&maxb, mega, NTHR, 0);
        if (oe == hipSuccess && maxb > 0 && ncu > 0) {
            int nblk = maxb * ncu;
            if (nblk > 512) nblk = 512;
            if (nblk >= 64) {
                int ph = -1, ly = 0;
                void* args[] = {&P, &ph, &ly};
                hipError_t e = hipLaunchCooperativeKernel(
                    (const void*)mega, dim3(nblk), dim3(NTHR), args, 0, stream);
                done = (e == hipSuccess);
            }
        }
    }
    if (!done) {
        auto fire = [&](int phase, int layer, int blocks) {
            hipLaunchKernelGGL(mega, dim3(blocks), dim3(NTHR), 0, stream, P, phase, layer);
        };
        fire(0, 0, 48);      // zero counters + flag
        fire(1, 0, 512);     // dtype detect
        fire(2, 0, 8192);    // fill ELL (one pass over H)
        fire(3, 0, 48);      // a = H^T r, p = H c
        fire(4, 0, 48);      // b = H a, q = H^T p
        fire(5, 0, 3072);    // degree vectors + X/Xs init + layer-0 out
        for (int L = 0; L < 2; L++)
            for (int s = 0; s < 6; s++)
                fire(6 + s, L, 3072);
    }
}

// Round 8
// 439.703 us; speedup vs baseline: 6.6471x; 6.6471x over previous
//
#include <hip/hip_runtime.h>
#include <hip/hip_bf16.h>

typedef unsigned short u16;
typedef unsigned int u32;

#define NU 8192
#define NI 4096
#define DE 64
#define ELL_U 80
#define ELL_I 112
#define EPSF 1e-7f
#define NTHR 256

__device__ __forceinline__ float b2f(__hip_bfloat16 x) { return __bfloat162float(x); }

struct KP {
    const void* Hp; const void* ue; const void* ie;
    const void* w0; const void* b0; const void* w1; const void* b1;
    void* out;
    u32* flag; int* cnt_u; int* cnt_i;
    u16* idx_u; u16* idx_i;
    float* a_f; float* p_f;
    float* dv_u; float* de1u; float* de2u;
    float* dv_i; float* de1i; float* de2i;
    float* Xu; float* Xi; float* Xsu; float* Xsi;
    float* T1u; float* TAu; float* TBu;
    float* T1i; float* TAi; float* TBi;
};

// 16-wide ILP gather with index prefetch. Optional per-source-row scale.
// Prefetch may overread <=32B past a row's live indices: stays inside the
// workspace (row strides are 16B-aligned; arrays 256B-padded). Values unused.
template <bool SC>
__device__ __forceinline__ float sp_row16(const u16* __restrict__ ip, int n,
                                          const float* __restrict__ src,
                                          const float* __restrict__ scale, int lane) {
    float a0 = 0.f, a1 = 0.f, a2 = 0.f, a3 = 0.f;
    float a4 = 0.f, a5 = 0.f, a6 = 0.f, a7 = 0.f;
    int p = 0;
    if (n >= 16) {
        uint4 ca = *(const uint4*)(ip);
        uint4 cb = *(const uint4*)(ip + 8);
        while (p + 16 <= n) {
            u32 w0 = ca.x, w1 = ca.y, w2 = ca.z, w3 = ca.w;
            u32 w4 = cb.x, w5 = cb.y, w6 = cb.z, w7 = cb.w;
            int c0 = w0 & 0xFFFF, c1 = w0 >> 16, c2 = w1 & 0xFFFF, c3 = w1 >> 16;
            int c4 = w2 & 0xFFFF, c5 = w2 >> 16, c6 = w3 & 0xFFFF, c7 = w3 >> 16;
            int c8 = w4 & 0xFFFF, c9 = w4 >> 16, cA = w5 & 0xFFFF, cB = w5 >> 16;
            int cC = w6 & 0xFFFF, cD = w6 >> 16, cE = w7 & 0xFFFF, cF = w7 >> 16;
            float g0 = src[((size_t)c0 << 6) + lane], g1 = src[((size_t)c1 << 6) + lane];
            float g2 = src[((size_t)c2 << 6) + lane], g3 = src[((size_t)c3 << 6) + lane];
            float g4 = src[((size_t)c4 << 6) + lane], g5 = src[((size_t)c5 << 6) + lane];
            float g6 = src[((size_t)c6 << 6) + lane], g7 = src[((size_t)c7 << 6) + lane];
            float g8 = src[((size_t)c8 << 6) + lane], g9 = src[((size_t)c9 << 6) + lane];
            float gA = src[((size_t)cA << 6) + lane], gB = src[((size_t)cB << 6) + lane];
            float gC = src[((size_t)cC << 6) + lane], gD = src[((size_t)cD << 6) + lane];
            float gE = src[((size_t)cE << 6) + lane], gF = src[((size_t)cF << 6) + lane];
            float s0 = 1.f, s1 = 1.f, s2 = 1.f, s3 = 1.f, s4 = 1.f, s5 = 1.f, s6 = 1.f, s7 = 1.f;
            float s8 = 1.f, s9 = 1.f, sA = 1.f, sB = 1.f, sC = 1.f, sD = 1.f, sE = 1.f, sF = 1.f;
            if (SC) {
                s0 = scale[c0]; s1 = scale[c1]; s2 = scale[c2]; s3 = scale[c3];
                s4 = scale[c4]; s5 = scale[c5]; s6 = scale[c6]; s7 = scale[c7];
                s8 = scale[c8]; s9 = scale[c9]; sA = scale[cA]; sB = scale[cB];
                sC = scale[cC]; sD = scale[cD]; sE = scale[cE]; sF = scale[cF];
            }
            p += 16;
            ca = *(const uint4*)(ip + p);        // prefetch before consuming
            cb = *(const uint4*)(ip + p + 8);
            if (SC) {
                a0 = fmaf(s0, g0, a0); a1 = fmaf(s1, g1, a1);
                a2 = fmaf(s2, g2, a2); a3 = fmaf(s3, g3, a3);
                a4 = fmaf(s4, g4, a4); a5 = fmaf(s5, g5, a5);
                a6 = fmaf(s6, g6, a6); a7 = fmaf(s7, g7, a7);
                a0 = fmaf(s8, g8, a0); a1 = fmaf(s9, g9, a1);
                a2 = fmaf(sA, gA, a2); a3 = fmaf(sB, gB, a3);
                a4 = fmaf(sC, gC, a4); a5 = fmaf(sD, gD, a5);
                a6 = fmaf(sE, gE, a6); a7 = fmaf(sF, gF, a7);
            } else {
                a0 += g0; a1 += g1; a2 += g2; a3 += g3;
                a4 += g4; a5 += g5; a6 += g6; a7 += g7;
                a0 += g8; a1 += g9; a2 += gA; a3 += gB;
                a4 += gC; a5 += gD; a6 += gE; a7 += gF;
            }
        }
    }
    if (p + 8 <= n) {
        uint4 ca = *(const uint4*)(ip + p);
        int c0 = ca.x & 0xFFFF, c1 = ca.x >> 16, c2 = ca.y & 0xFFFF, c3 = ca.y >> 16;
        int c4 = ca.z & 0xFFFF, c5 = ca.z >> 16, c6 = ca.w & 0xFFFF, c7 = ca.w >> 16;
        float f0 = SC ? scale[c0] : 1.f, f1 = SC ? scale[c1] : 1.f;
        float f2 = SC ? scale[c2] : 1.f, f3 = SC ? scale[c3] : 1.f;
        float f4 = SC ? scale[c4] : 1.f, f5 = SC ? scale[c5] : 1.f;
        float f6 = SC ? scale[c6] : 1.f, f7 = SC ? scale[c7] : 1.f;
        a0 = fmaf(f0, src[((size_t)c0 << 6) + lane], a0);
        a1 = fmaf(f1, src[((size_t)c1 << 6) + lane], a1);
        a2 = fmaf(f2, src[((size_t)c2 << 6) + lane], a2);
        a3 = fmaf(f3, src[((size_t)c3 << 6) + lane], a3);
        a4 = fmaf(f4, src[((size_t)c4 << 6) + lane], a4);
        a5 = fmaf(f5, src[((size_t)c5 << 6) + lane], a5);
        a6 = fmaf(f6, src[((size_t)c6 << 6) + lane], a6);
        a7 = fmaf(f7, src[((size_t)c7 << 6) + lane], a7);
        p += 8;
    }
    if (p + 4 <= n) {
        ushort4 cc = *(const ushort4*)(ip + p);
        float f0 = SC ? scale[cc.x] : 1.f, f1 = SC ? scale[cc.y] : 1.f;
        float f2 = SC ? scale[cc.z] : 1.f, f3 = SC ? scale[cc.w] : 1.f;
        a0 = fmaf(f0, src[((size_t)cc.x << 6) + lane], a0);
        a1 = fmaf(f1, src[((size_t)cc.y << 6) + lane], a1);
        a2 = fmaf(f2, src[((size_t)cc.z << 6) + lane], a2);
        a3 = fmaf(f3, src[((size_t)cc.w << 6) + lane], a3);
        p += 4;
    }
    for (; p < n; p++) {
        int c = ip[p];
        float f = SC ? scale[c] : 1.f;
        a4 = fmaf(f, src[((size_t)c << 6) + lane], a4);
    }
    return ((a0 + a1) + (a2 + a3)) + ((a4 + a5) + (a6 + a7));
}

__device__ __forceinline__ float sv_row_f(const u16* ip, int n, const float* sv) {
    float a0 = 0.f, a1 = 0.f, a2 = 0.f, a3 = 0.f;
    int p = 0;
    for (; p + 4 <= n; p += 4) {
        ushort4 cc = *(const ushort4*)(ip + p);
        a0 += sv[cc.x]; a1 += sv[cc.y]; a2 += sv[cc.z]; a3 += sv[cc.w];
    }
    for (; p < n; p++) a0 += sv[ip[p]];
    return (a0 + a1) + (a2 + a3);
}

__device__ __forceinline__ float sv_row_i(const u16* ip, int n, const int* sv) {
    float a0 = 0.f, a1 = 0.f, a2 = 0.f, a3 = 0.f;
    int p = 0;
    for (; p + 4 <= n; p += 4) {
        ushort4 cc = *(const ushort4*)(ip + p);
        a0 += (float)sv[cc.x]; a1 += (float)sv[cc.y];
        a2 += (float)sv[cc.z]; a3 += (float)sv[cc.w];
    }
    for (; p < n; p++) a0 += (float)sv[ip[p]];
    return (a0 + a1) + (a2 + a3);
}

// ---------------- phases ----------------

// P0: zero counters + dtype vote. H entries are exactly 0.0/1.0: fp32 words
// 0x00000000/0x3F800000 (low u16 always 0); bf16 pairs expose 0x3F80 in the
// low u16 for even-col nnz. Vote via atomicMin (bf16->1, fp32->2): works on
// 0xAA-poisoned flag with no pre-zero; one atomic per wave.
__device__ __forceinline__ void ph_zero_detect(const KP& P, int t, int stride) {
    for (int e = t; e < NU + NI; e += stride) {
        if (e < NU) P.cnt_u[e] = 0;
        else P.cnt_i[e - NU] = 0;
    }
    bool hit = false;
    for (int e = t; e < 131072; e += stride) {
        u32 w = ((const u32*)P.Hp)[e];
        hit |= ((w & 0xFFFFu) == 0x3F80u);
    }
    if (__any(hit ? 1 : 0)) { if ((t & 63) == 0) atomicMin(P.flag, 1u); }
    else                    { if ((t & 63) == 0) atomicMin(P.flag, 2u); }
}

__device__ __forceinline__ void ph_fill(const KP& P, int t, int stride, int bf) {
    for (int q = t; q < (NU * NI / 8); q += stride) {
        int flat = q << 3;
        int i = flat >> 12;    // user row
        int j0 = flat & 4095;  // col base
        u32 words[8];
        if (bf) {
            uint4 v = ((const uint4*)P.Hp)[q];
            u32 p4[4] = {v.x, v.y, v.z, v.w};
#pragma unroll
            for (int k = 0; k < 4; k++) {
                words[2 * k] = p4[k] & 0xFFFFu;
                words[2 * k + 1] = p4[k] >> 16;
            }
        } else {
            uint4 a = ((const uint4*)P.Hp)[2 * q];
            uint4 b = ((const uint4*)P.Hp)[2 * q + 1];
            words[0] = a.x; words[1] = a.y; words[2] = a.z; words[3] = a.w;
            words[4] = b.x; words[5] = b.y; words[6] = b.z; words[7] = b.w;
        }
#pragma unroll
        for (int e = 0; e < 8; e++) {
            if (words[e]) {
                int j = j0 + e;
                int pu = atomicAdd(&P.cnt_u[i], 1);
                if (pu < ELL_U) P.idx_u[i * ELL_U + pu] = (u16)j;
                int pi = atomicAdd(&P.cnt_i[j], 1);
                if (pi < ELL_I) P.idx_i[j * ELL_I + pi] = (u16)i;
            }
        }
    }
}

// P2: a = H^T r (item rows), p = H c (user rows)  +  fp32 X copies + layer-0 out
__device__ __forceinline__ void ph_spmv1_xinit(const KP& P, int t, int stride, int bf) {
    for (int r = t; r < NI + NU; r += stride) {
        if (r < NI) {
            int n = min(P.cnt_i[r], ELL_I);
            P.a_f[r] = sv_row_i(P.idx_i + (size_t)r * ELL_I, n, P.cnt_u);
        } else {
            int u = r - NI;
            int n = min(P.cnt_u[u], ELL_U);
            P.p_f[u] = sv_row_i(P.idx_u + (size_t)u * ELL_U, n, P.cnt_i);
        }
    }
    for (int e = t; e < (NU + NI) * DE; e += stride) {
        if (e < NU * DE) {
            int i = e >> 6, l = e & 63;
            float v = bf ? b2f(((const __hip_bfloat16*)P.ue)[e]) : ((const float*)P.ue)[e];
            P.Xu[e] = v;
            size_t o = (size_t)i * 192 + l;
            if (bf) ((__hip_bfloat16*)P.out)[o] = __float2bfloat16(v);
            else ((float*)P.out)[o] = v;
        } else {
            int s = e - NU * DE;
            int i = s >> 6, l = s & 63;
            float v = bf ? b2f(((const __hip_bfloat16*)P.ie)[s]) : ((const float*)P.ie)[s];
            P.Xi[s] = v;
            size_t o = (size_t)(NU + i) * 192 + l;
            if (bf) ((__hip_bfloat16*)P.out)[o] = __float2bfloat16(v);
            else ((float*)P.out)[o] = v;
        }
    }
}

// P3: b = H a (user rows), q = H^T p (item rows) + ALL degree vectors in-thread
__device__ __forceinline__ void ph_spmv2_deg(const KP& P, int t, int stride) {
    for (int r = t; r < NU + NI; r += stride) {
        if (r < NU) {
            int n = min(P.cnt_u[r], ELL_U);
            float b = sv_row_f(P.idx_u + (size_t)r * ELL_U, n, P.a_f);
            float rr = (float)P.cnt_u[r];
            P.dv_u[r] = 1.0f / sqrtf(rr + b + EPSF);
            P.de1i[r] = 1.0f / (rr + EPSF);
            P.de2i[r] = 1.0f / (b + EPSF);
        } else {
            int u = r - NU;
            int n = min(P.cnt_i[u], ELL_I);
            float q = sv_row_f(P.idx_i + (size_t)u * ELL_I, n, P.p_f);
            float cd = (float)P.cnt_i[u];
            P.dv_i[u] = 1.0f / sqrtf(cd + q + EPSF);
            P.de1u[u] = 1.0f / (cd + EPSF);
            P.de2u[u] = 1.0f / (q + EPSF);
        }
    }
}

// MODE 0: dst=acc ; 1: dst=ev[row]*acc ; 2: dst=acc+ev[row]*ax[o] ; 3: scaled-gather, dst=acc
template <int MODE>
__device__ __forceinline__ void sp_stage(int gw, int nw, int lane,
    const int* cA, const u16* iA, int eA, int nA, const float* sA, float* dA,
    const float* vA, const float* xA,
    const int* cB, const u16* iB, int eB, int nB, const float* sB, float* dB,
    const float* vB, const float* xB) {
    for (int r = gw; r < nA + nB; r += nw) {
        bool isA = r < nA;
        const int* c = isA ? cA : cB;
        const u16* idx = isA ? iA : iB;
        int ell = isA ? eA : eB;
        const float* src = isA ? sA : sB;
        float* dst = isA ? dA : dB;
        const float* ev = isA ? vA : vB;
        int row = isA ? r : r - nA;
        int n = min(c[row], ell);
        float acc;
        if (MODE == 3) acc = sp_row16<true>(idx + (size_t)row * ell, n, src, ev, lane);
        else acc = sp_row16<false>(idx + (size_t)row * ell, n, src, 0, lane);
        size_t o = ((size_t)row << 6) + lane;
        if (MODE == 1) {
            dst[o] = ev[row] * acc;
        } else if (MODE == 2) {
            const float* ax = isA ? xA : xB;
            dst[o] = acc + ev[row] * ax[o];
        } else {
            dst[o] = acc;
        }
    }
}

// s6: M = dv*acc + X ; Xnext = M@w + b ; Xs = dv*Xnext ; emit out cols
__device__ __forceinline__ void sp_final(int gw, int nw, int lane, int bf,
    const KP& P, const void* w, const void* bias, int coloff) {
    for (int r = gw; r < NU + NI; r += nw) {
        bool isA = r < NU;
        const int* c = isA ? P.cnt_u : P.cnt_i;
        const u16* idx = isA ? P.idx_u : P.idx_i;
        int ell = isA ? ELL_U : ELL_I;
        const float* src = isA ? P.TBu : P.TBi;
        const float* dvv = isA ? P.dv_u : P.dv_i;
        float* X = isA ? P.Xu : P.Xi;
        float* Xs = isA ? P.Xsu : P.Xsi;
        size_t ob = isA ? (size_t)0 : (size_t)NU * 192;
        int row = isA ? r : r - NU;
        int n = min(c[row], ell);
        float acc = sp_row16<false>(idx + (size_t)row * ell, n, src, 0, lane);
        size_t o = ((size_t)row << 6) + lane;
        float dvr = dvv[row];
        float m = dvr * acc + X[o];
        float x0, x1 = 0.f, x2 = 0.f, x3 = 0.f;
        if (bf) {
            const __hip_bfloat16* __restrict__ wp = (const __hip_bfloat16*)w;
            x0 = b2f(((const __hip_bfloat16*)bias)[lane]);
            for (int k = 0; k < 64; k += 4) {
                x0 = fmaf(__shfl(m, k, 64), b2f(wp[(k << 6) + lane]), x0);
                x1 = fmaf(__shfl(m, k + 1, 64), b2f(wp[((k + 1) << 6) + lane]), x1);
                x2 = fmaf(__shfl(m, k + 2, 64), b2f(wp[((k + 2) << 6) + lane]), x2);
                x3 = fmaf(__shfl(m, k + 3, 64), b2f(wp[((k + 3) << 6) + lane]), x3);
            }
        } else {
            const float* __restrict__ wp = (const float*)w;
            x0 = ((const float*)bias)[lane];
            for (int k = 0; k < 64; k += 4) {
                x0 = fmaf(__shfl(m, k, 64), wp[(k << 6) + lane], x0);
                x1 = fmaf(__shfl(m, k + 1, 64), wp[((k + 1) << 6) + lane], x1);
                x2 = fmaf(__shfl(m, k + 2, 64), wp[((k + 2) << 6) + lane], x2);
                x3 = fmaf(__shfl(m, k + 3, 64), wp[((k + 3) << 6) + lane], x3);
            }
        }
        float xn = (x0 + x1) + (x2 + x3);
        X[o] = xn;
        Xs[o] = dvr * xn;  // premultiplied for next layer's s1
        size_t oo = ob + (size_t)row * 192 + coloff + lane;
        if (bf) ((__hip_bfloat16*)P.out)[oo] = __float2bfloat16(xn);
        else ((float*)P.out)[oo] = xn;
    }
}

__device__ __forceinline__ void ph_stage(const KP& P, int layer, int s,
                                         int gw, int nw, int lane, int bf) {
    switch (s) {
        case 0:  // T1 = A^T (dv o X): layer0 scaled-gather of X, layer1 plain gather of Xs
            if (layer == 0)
                sp_stage<3>(gw, nw, lane,
                            P.cnt_i, P.idx_i, ELL_I, NI, P.Xu, P.T1u, P.dv_u, 0,
                            P.cnt_u, P.idx_u, ELL_U, NU, P.Xi, P.T1i, P.dv_i, 0);
            else
                sp_stage<0>(gw, nw, lane,
                            P.cnt_i, P.idx_i, ELL_I, NI, P.Xsu, P.T1u, 0, 0,
                            P.cnt_u, P.idx_u, ELL_U, NU, P.Xsi, P.T1i, 0, 0);
            break;
        case 1:  // T2 = A T1
            sp_stage<0>(gw, nw, lane,
                        P.cnt_u, P.idx_u, ELL_U, NU, P.T1u, P.TAu, 0, 0,
                        P.cnt_i, P.idx_i, ELL_I, NI, P.T1i, P.TAi, 0, 0);
            break;
        case 2:  // T3 = de2 o (A^T T2)
            sp_stage<1>(gw, nw, lane,
                        P.cnt_i, P.idx_i, ELL_I, NI, P.TAu, P.TBu, P.de2u, 0,
                        P.cnt_u, P.idx_u, ELL_U, NU, P.TAi, P.TBi, P.de2i, 0);
            break;
        case 3:  // T4 = A T3
            sp_stage<0>(gw, nw, lane,
                        P.cnt_u, P.idx_u, ELL_U, NU, P.TBu, P.TAu, 0, 0,
                        P.cnt_i, P.idx_i, ELL_I, NI, P.TBi, P.TAi, 0, 0);
            break;
        case 4:  // S = A^T T4 + de1 o T1
            sp_stage<2>(gw, nw, lane,
                        P.cnt_i, P.idx_i, ELL_I, NI, P.TAu, P.TBu, P.de1u, P.T1u,
                        P.cnt_u, P.idx_u, ELL_U, NU, P.TAi, P.TBi, P.de1i, P.T1i);
            break;
        default:
            sp_final(gw, nw, lane, bf, P, layer ? P.w1 : P.w0, layer ? P.b1 : P.b0,
                     64 + 64 * layer);
            break;
    }
}

__global__ __launch_bounds__(NTHR, 2) void mega(KP P, int phase, int layer) {
    const int t = blockIdx.x * NTHR + threadIdx.x;
    const int stride = gridDim.x * NTHR;
    const int lane = threadIdx.x & 63;
    const int gw = t >> 6;
    const int nw = stride >> 6;
    int bf = (phase >= 1) ? (P.flag[0] == 1u) : 0;
    switch (phase) {
        case 0: ph_zero_detect(P, t, stride); break;
        case 1: ph_fill(P, t, stride, bf); break;
        case 2: ph_spmv1_xinit(P, t, stride, bf); break;
        case 3: ph_spmv2_deg(P, t, stride); break;
        default: ph_stage(P, layer, phase - 4, gw, nw, lane, bf); break;
    }
}

// ---------------- host ----------------

extern "C" void kernel_launch(void* const* d_in, const int* in_sizes, int n_in,
                              void* d_out, int out_size, void* d_ws, size_t ws_size,
                              hipStream_t stream) {
    char* ws = (char*)d_ws;
    size_t off = 0;
    auto alloc = [&](size_t bytes) -> char* {
        char* p = ws + off;
        off = (off + bytes + 255) & ~(size_t)255;
        return p;
    };

    KP P;
    P.Hp = d_in[0]; P.ue = d_in[1]; P.ie = d_in[2];
    P.w0 = d_in[3]; P.b0 = d_in[4]; P.w1 = d_in[5]; P.b1 = d_in[6];
    P.out = d_out;
    P.flag = (u32*)alloc(256);
    P.cnt_u = (int*)alloc(NU * 4);
    P.cnt_i = (int*)alloc(NI * 4);
    P.idx_u = (u16*)alloc((size_t)NU * ELL_U * 2 + 256);
    P.idx_i = (u16*)alloc((size_t)NI * ELL_I * 2 + 256);
    P.a_f = (float*)alloc(NI * 4);
    P.p_f = (float*)alloc(NU * 4);
    P.dv_u = (float*)alloc(NU * 4);
    P.de1u = (float*)alloc(NI * 4);
    P.de2u = (float*)alloc(NI * 4);
    P.dv_i = (float*)alloc(NI * 4);
    P.de1i = (float*)alloc(NU * 4);
    P.de2i = (float*)alloc(NU * 4);
    P.Xu = (float*)alloc((size_t)NU * DE * 4);
    P.Xi = (float*)alloc((size_t)NI * DE * 4);
    P.Xsu = (float*)alloc((size_t)NU * DE * 4);
    P.Xsi = (float*)alloc((size_t)NI * DE * 4);
    P.T1u = (float*)alloc((size_t)NI * DE * 4);
    P.TAu = (float*)alloc((size_t)NU * DE * 4);
    P.TBu = (float*)alloc((size_t)NI * DE * 4);
    P.T1i = (float*)alloc((size_t)NU * DE * 4);
    P.TAi = (float*)alloc((size_t)NI * DE * 4);
    P.TBi = (float*)alloc((size_t)NU * DE * 4);
    (void)ws_size; (void)n_in; (void)in_sizes; (void)out_size;

    auto fire = [&](int phase, int layer, int blocks) {
        hipLaunchKernelGGL(mega, dim3(blocks), dim3(NTHR), 0, stream, P, phase, layer);
    };
    fire(0, 0, 512);   // zero counters + dtype vote
    fire(1, 0, 8192);  // fill ELL (one pass over H)
    fire(2, 0, 3072);  // a/p spmv + X fp32 copies + layer-0 out cols
    fire(3, 0, 48);    // b/q spmv + all degree vectors
    for (int L = 0; L < 2; L++)
        for (int s = 0; s < 6; s++)
            fire(4 + s, L, 2048);  // 12 SpMM stages
}

// Round 9
// 436.680 us; speedup vs baseline: 6.6931x; 1.0069x over previous
//
#include <hip/hip_runtime.h>
#include <hip/hip_bf16.h>

typedef unsigned short u16;
typedef unsigned int u32;

#define NU 8192
#define NI 4096
#define DE 64
#define ELL_U 80
#define ELL_I 112
#define EPSF 1e-7f
#define NTHR 256

__device__ __forceinline__ float b2f(__hip_bfloat16 x) { return __bfloat162float(x); }

struct KP {
    const void* Hp; const void* ue; const void* ie;
    const void* w0; const void* b0; const void* w1; const void* b1;
    void* out;
    u32* flag; int* cnt_u; int* cnt_i;
    u16* idx_u; u16* idx_i;
    float* a_f; float* p_f;
    float* dv_u; float* de1u; float* de2u;
    float* dv_i; float* de1i; float* de2i;
    float* Xu; float* Xi; float* Xsu; float* Xsi;
    float* T1u; float* TAu; float* TBu;
    float* T1i; float* TAi; float* TBi;
};

// 16-wide ILP gather with index prefetch. Optional per-source-row scale.
// Prefetch may overread <=32B past a row's live indices: stays inside the
// workspace (row strides are 16B-aligned; arrays 256B-padded). Values unused.
template <bool SC>
__device__ __forceinline__ float sp_row16(const u16* __restrict__ ip, int n,
                                          const float* __restrict__ src,
                                          const float* __restrict__ scale, int lane) {
    float a0 = 0.f, a1 = 0.f, a2 = 0.f, a3 = 0.f;
    float a4 = 0.f, a5 = 0.f, a6 = 0.f, a7 = 0.f;
    int p = 0;
    if (n >= 16) {
        uint4 ca = *(const uint4*)(ip);
        uint4 cb = *(const uint4*)(ip + 8);
        while (p + 16 <= n) {
            u32 w0 = ca.x, w1 = ca.y, w2 = ca.z, w3 = ca.w;
            u32 w4 = cb.x, w5 = cb.y, w6 = cb.z, w7 = cb.w;
            int c0 = w0 & 0xFFFF, c1 = w0 >> 16, c2 = w1 & 0xFFFF, c3 = w1 >> 16;
            int c4 = w2 & 0xFFFF, c5 = w2 >> 16, c6 = w3 & 0xFFFF, c7 = w3 >> 16;
            int c8 = w4 & 0xFFFF, c9 = w4 >> 16, cA = w5 & 0xFFFF, cB = w5 >> 16;
            int cC = w6 & 0xFFFF, cD = w6 >> 16, cE = w7 & 0xFFFF, cF = w7 >> 16;
            float g0 = src[((size_t)c0 << 6) + lane], g1 = src[((size_t)c1 << 6) + lane];
            float g2 = src[((size_t)c2 << 6) + lane], g3 = src[((size_t)c3 << 6) + lane];
            float g4 = src[((size_t)c4 << 6) + lane], g5 = src[((size_t)c5 << 6) + lane];
            float g6 = src[((size_t)c6 << 6) + lane], g7 = src[((size_t)c7 << 6) + lane];
            float g8 = src[((size_t)c8 << 6) + lane], g9 = src[((size_t)c9 << 6) + lane];
            float gA = src[((size_t)cA << 6) + lane], gB = src[((size_t)cB << 6) + lane];
            float gC = src[((size_t)cC << 6) + lane], gD = src[((size_t)cD << 6) + lane];
            float gE = src[((size_t)cE << 6) + lane], gF = src[((size_t)cF << 6) + lane];
            float s0 = 1.f, s1 = 1.f, s2 = 1.f, s3 = 1.f, s4 = 1.f, s5 = 1.f, s6 = 1.f, s7 = 1.f;
            float s8 = 1.f, s9 = 1.f, sA = 1.f, sB = 1.f, sC = 1.f, sD = 1.f, sE = 1.f, sF = 1.f;
            if (SC) {
                s0 = scale[c0]; s1 = scale[c1]; s2 = scale[c2]; s3 = scale[c3];
                s4 = scale[c4]; s5 = scale[c5]; s6 = scale[c6]; s7 = scale[c7];
                s8 = scale[c8]; s9 = scale[c9]; sA = scale[cA]; sB = scale[cB];
                sC = scale[cC]; sD = scale[cD]; sE = scale[cE]; sF = scale[cF];
            }
            p += 16;
            ca = *(const uint4*)(ip + p);        // prefetch before consuming
            cb = *(const uint4*)(ip + p + 8);
            if (SC) {
                a0 = fmaf(s0, g0, a0); a1 = fmaf(s1, g1, a1);
                a2 = fmaf(s2, g2, a2); a3 = fmaf(s3, g3, a3);
                a4 = fmaf(s4, g4, a4); a5 = fmaf(s5, g5, a5);
                a6 = fmaf(s6, g6, a6); a7 = fmaf(s7, g7, a7);
                a0 = fmaf(s8, g8, a0); a1 = fmaf(s9, g9, a1);
                a2 = fmaf(sA, gA, a2); a3 = fmaf(sB, gB, a3);
                a4 = fmaf(sC, gC, a4); a5 = fmaf(sD, gD, a5);
                a6 = fmaf(sE, gE, a6); a7 = fmaf(sF, gF, a7);
            } else {
                a0 += g0; a1 += g1; a2 += g2; a3 += g3;
                a4 += g4; a5 += g5; a6 += g6; a7 += g7;
                a0 += g8; a1 += g9; a2 += gA; a3 += gB;
                a4 += gC; a5 += gD; a6 += gE; a7 += gF;
            }
        }
    }
    if (p + 8 <= n) {
        uint4 ca = *(const uint4*)(ip + p);
        int c0 = ca.x & 0xFFFF, c1 = ca.x >> 16, c2 = ca.y & 0xFFFF, c3 = ca.y >> 16;
        int c4 = ca.z & 0xFFFF, c5 = ca.z >> 16, c6 = ca.w & 0xFFFF, c7 = ca.w >> 16;
        float f0 = SC ? scale[c0] : 1.f, f1 = SC ? scale[c1] : 1.f;
        float f2 = SC ? scale[c2] : 1.f, f3 = SC ? scale[c3] : 1.f;
        float f4 = SC ? scale[c4] : 1.f, f5 = SC ? scale[c5] : 1.f;
        float f6 = SC ? scale[c6] : 1.f, f7 = SC ? scale[c7] : 1.f;
        a0 = fmaf(f0, src[((size_t)c0 << 6) + lane], a0);
        a1 = fmaf(f1, src[((size_t)c1 << 6) + lane], a1);
        a2 = fmaf(f2, src[((size_t)c2 << 6) + lane], a2);
        a3 = fmaf(f3, src[((size_t)c3 << 6) + lane], a3);
        a4 = fmaf(f4, src[((size_t)c4 << 6) + lane], a4);
        a5 = fmaf(f5, src[((size_t)c5 << 6) + lane], a5);
        a6 = fmaf(f6, src[((size_t)c6 << 6) + lane], a6);
        a7 = fmaf(f7, src[((size_t)c7 << 6) + lane], a7);
        p += 8;
    }
    if (p + 4 <= n) {
        ushort4 cc = *(const ushort4*)(ip + p);
        float f0 = SC ? scale[cc.x] : 1.f, f1 = SC ? scale[cc.y] : 1.f;
        float f2 = SC ? scale[cc.z] : 1.f, f3 = SC ? scale[cc.w] : 1.f;
        a0 = fmaf(f0, src[((size_t)cc.x << 6) + lane], a0);
        a1 = fmaf(f1, src[((size_t)cc.y << 6) + lane], a1);
        a2 = fmaf(f2, src[((size_t)cc.z << 6) + lane], a2);
        a3 = fmaf(f3, src[((size_t)cc.w << 6) + lane], a3);
        p += 4;
    }
    for (; p < n; p++) {
        int c = ip[p];
        float f = SC ? scale[c] : 1.f;
        a4 = fmaf(f, src[((size_t)c << 6) + lane], a4);
    }
    return ((a0 + a1) + (a2 + a3)) + ((a4 + a5) + (a6 + a7));
}

__device__ __forceinline__ float sv_row_f(const u16* ip, int n, const float* sv) {
    float a0 = 0.f, a1 = 0.f, a2 = 0.f, a3 = 0.f;
    int p = 0;
    for (; p + 4 <= n; p += 4) {
        ushort4 cc = *(const ushort4*)(ip + p);
        a0 += sv[cc.x]; a1 += sv[cc.y]; a2 += sv[cc.z]; a3 += sv[cc.w];
    }
    for (; p < n; p++) a0 += sv[ip[p]];
    return (a0 + a1) + (a2 + a3);
}

__device__ __forceinline__ float sv_row_i(const u16* ip, int n, const int* sv) {
    float a0 = 0.f, a1 = 0.f, a2 = 0.f, a3 = 0.f;
    int p = 0;
    for (; p + 4 <= n; p += 4) {
        ushort4 cc = *(const ushort4*)(ip + p);
        a0 += (float)sv[cc.x]; a1 += (float)sv[cc.y];
        a2 += (float)sv[cc.z]; a3 += (float)sv[cc.w];
    }
    for (; p < n; p++) a0 += (float)sv[ip[p]];
    return (a0 + a1) + (a2 + a3);
}

// ---------------- phases ----------------

// P0: zero counters + dtype vote. H entries are exactly 0.0/1.0: fp32 words
// 0x00000000/0x3F800000 (low u16 always 0); bf16 pairs expose 0x3F80 in the
// low u16 for even-col nnz. Vote via atomicMin (bf16->1, fp32->2): works on
// 0xAA-poisoned flag with no pre-zero; one atomic per wave.
__device__ __forceinline__ void ph_zero_detect(const KP& P, int t, int stride) {
    for (int e = t; e < NU + NI; e += stride) {
        if (e < NU) P.cnt_u[e] = 0;
        else P.cnt_i[e - NU] = 0;
    }
    bool hit = false;
    for (int e = t; e < 131072; e += stride) {
        u32 w = ((const u32*)P.Hp)[e];
        hit |= ((w & 0xFFFFu) == 0x3F80u);
    }
    if (__any(hit ? 1 : 0)) { if ((t & 63) == 0) atomicMin(P.flag, 1u); }
    else                    { if ((t & 63) == 0) atomicMin(P.flag, 2u); }
}

// P1: fill ELL lists, one pass over H. All 64 lanes of a wave cover 512
// consecutive cols of ONE user row -> aggregate cnt_u to a single atomic per
// wave via prefix scan; item-side atomics hit 64 distinct counters (no
// same-address serialization within a wave).
__device__ __forceinline__ void ph_fill(const KP& P, int t, int lane, int bf) {
    int q = t;  // 16384x256 grid = one 8-col group per thread
    if (q >= (NU * NI / 8)) return;
    int flat = q << 3;
    int i = flat >> 12;    // user row (wave-uniform: 512 cols per wave)
    int j0 = flat & 4095;  // col base
    u32 words[8];
    if (bf) {
        uint4 v = ((const uint4*)P.Hp)[q];
        u32 p4[4] = {v.x, v.y, v.z, v.w};
#pragma unroll
        for (int k = 0; k < 4; k++) {
            words[2 * k] = p4[k] & 0xFFFFu;
            words[2 * k + 1] = p4[k] >> 16;
        }
    } else {
        uint4 a = ((const uint4*)P.Hp)[2 * q];
        uint4 b = ((const uint4*)P.Hp)[2 * q + 1];
        words[0] = a.x; words[1] = a.y; words[2] = a.z; words[3] = a.w;
        words[4] = b.x; words[5] = b.y; words[6] = b.z; words[7] = b.w;
    }
    u32 m = 0;
#pragma unroll
    for (int e = 0; e < 8; e++)
        if (words[e]) m |= (1u << e);
    int nl = __popc(m);
    // inclusive prefix scan of nl across the wave
    int pre = nl;
#pragma unroll
    for (int d = 1; d < 64; d <<= 1) {
        int v = __shfl_up(pre, d, 64);
        if (lane >= d) pre += v;
    }
    int total = __shfl(pre, 63, 64);
    if (total == 0) return;
    int base = 0;
    if (lane == 0) base = atomicAdd(&P.cnt_u[i], total);
    base = __shfl(base, 0, 64);
    int pos = base + (pre - nl);
    if (m) {
#pragma unroll
        for (int e = 0; e < 8; e++) {
            if (m & (1u << e)) {
                int j = j0 + e;
                if (pos < ELL_U) P.idx_u[i * ELL_U + pos] = (u16)j;
                pos++;
                int pi = atomicAdd(&P.cnt_i[j], 1);
                if (pi < ELL_I) P.idx_i[j * ELL_I + pi] = (u16)i;
            }
        }
    }
}

// P2: a = H^T r (item rows), p = H c (user rows)  +  fp32 X copies + layer-0 out
__device__ __forceinline__ void ph_spmv1_xinit(const KP& P, int t, int stride, int bf) {
    for (int r = t; r < NI + NU; r += stride) {
        if (r < NI) {
            int n = min(P.cnt_i[r], ELL_I);
            P.a_f[r] = sv_row_i(P.idx_i + (size_t)r * ELL_I, n, P.cnt_u);
        } else {
            int u = r - NI;
            int n = min(P.cnt_u[u], ELL_U);
            P.p_f[u] = sv_row_i(P.idx_u + (size_t)u * ELL_U, n, P.cnt_i);
        }
    }
    for (int e = t; e < (NU + NI) * DE; e += stride) {
        if (e < NU * DE) {
            int i = e >> 6, l = e & 63;
            float v = bf ? b2f(((const __hip_bfloat16*)P.ue)[e]) : ((const float*)P.ue)[e];
            P.Xu[e] = v;
            size_t o = (size_t)i * 192 + l;
            if (bf) ((__hip_bfloat16*)P.out)[o] = __float2bfloat16(v);
            else ((float*)P.out)[o] = v;
        } else {
            int s = e - NU * DE;
            int i = s >> 6, l = s & 63;
            float v = bf ? b2f(((const __hip_bfloat16*)P.ie)[s]) : ((const float*)P.ie)[s];
            P.Xi[s] = v;
            size_t o = (size_t)(NU + i) * 192 + l;
            if (bf) ((__hip_bfloat16*)P.out)[o] = __float2bfloat16(v);
            else ((float*)P.out)[o] = v;
        }
    }
}

// P3: b = H a (user rows), q = H^T p (item rows) + ALL degree vectors in-thread
__device__ __forceinline__ void ph_spmv2_deg(const KP& P, int t, int stride) {
    for (int r = t; r < NU + NI; r += stride) {
        if (r < NU) {
            int n = min(P.cnt_u[r], ELL_U);
            float b = sv_row_f(P.idx_u + (size_t)r * ELL_U, n, P.a_f);
            float rr = (float)P.cnt_u[r];
            P.dv_u[r] = 1.0f / sqrtf(rr + b + EPSF);
            P.de1i[r] = 1.0f / (rr + EPSF);
            P.de2i[r] = 1.0f / (b + EPSF);
        } else {
            int u = r - NU;
            int n = min(P.cnt_i[u], ELL_I);
            float q = sv_row_f(P.idx_i + (size_t)u * ELL_I, n, P.p_f);
            float cd = (float)P.cnt_i[u];
            P.dv_i[u] = 1.0f / sqrtf(cd + q + EPSF);
            P.de1u[u] = 1.0f / (cd + EPSF);
            P.de2u[u] = 1.0f / (q + EPSF);
        }
    }
}

// MODE 0: dst=acc ; 1: dst=ev[row]*acc ; 2: dst=acc+ev[row]*ax[o] ; 3: scaled-gather, dst=acc
template <int MODE>
__device__ __forceinline__ void sp_stage(int gw, int nw, int lane,
    const int* cA, const u16* iA, int eA, int nA, const float* sA, float* dA,
    const float* vA, const float* xA,
    const int* cB, const u16* iB, int eB, int nB, const float* sB, float* dB,
    const float* vB, const float* xB) {
    for (int r = gw; r < nA + nB; r += nw) {
        bool isA = r < nA;
        const int* c = isA ? cA : cB;
        const u16* idx = isA ? iA : iB;
        int ell = isA ? eA : eB;
        const float* src = isA ? sA : sB;
        float* dst = isA ? dA : dB;
        const float* ev = isA ? vA : vB;
        int row = isA ? r : r - nA;
        int n = min(c[row], ell);
        float acc;
        if (MODE == 3) acc = sp_row16<true>(idx + (size_t)row * ell, n, src, ev, lane);
        else acc = sp_row16<false>(idx + (size_t)row * ell, n, src, 0, lane);
        size_t o = ((size_t)row << 6) + lane;
        if (MODE == 1) {
            dst[o] = ev[row] * acc;
        } else if (MODE == 2) {
            const float* ax = isA ? xA : xB;
            dst[o] = acc + ev[row] * ax[o];
        } else {
            dst[o] = acc;
        }
    }
}

// s6: M = dv*acc + X ; Xnext = M@w + b ; Xs = dv*Xnext ; emit out cols
__device__ __forceinline__ void sp_final(int gw, int nw, int lane, int bf,
    const KP& P, const void* w, const void* bias, int coloff) {
    for (int r = gw; r < NU + NI; r += nw) {
        bool isA = r < NU;
        const int* c = isA ? P.cnt_u : P.cnt_i;
        const u16* idx = isA ? P.idx_u : P.idx_i;
        int ell = isA ? ELL_U : ELL_I;
        const float* src = isA ? P.TBu : P.TBi;
        const float* dvv = isA ? P.dv_u : P.dv_i;
        float* X = isA ? P.Xu : P.Xi;
        float* Xs = isA ? P.Xsu : P.Xsi;
        size_t ob = isA ? (size_t)0 : (size_t)NU * 192;
        int row = isA ? r : r - NU;
        int n = min(c[row], ell);
        float acc = sp_row16<false>(idx + (size_t)row * ell, n, src, 0, lane);
        size_t o = ((size_t)row << 6) + lane;
        float dvr = dvv[row];
        float m = dvr * acc + X[o];
        float x0, x1 = 0.f, x2 = 0.f, x3 = 0.f;
        if (bf) {
            const __hip_bfloat16* __restrict__ wp = (const __hip_bfloat16*)w;
            x0 = b2f(((const __hip_bfloat16*)bias)[lane]);
            for (int k = 0; k < 64; k += 4) {
                x0 = fmaf(__shfl(m, k, 64), b2f(wp[(k << 6) + lane]), x0);
                x1 = fmaf(__shfl(m, k + 1, 64), b2f(wp[((k + 1) << 6) + lane]), x1);
                x2 = fmaf(__shfl(m, k + 2, 64), b2f(wp[((k + 2) << 6) + lane]), x2);
                x3 = fmaf(__shfl(m, k + 3, 64), b2f(wp[((k + 3) << 6) + lane]), x3);
            }
        } else {
            const float* __restrict__ wp = (const float*)w;
            x0 = ((const float*)bias)[lane];
            for (int k = 0; k < 64; k += 4) {
                x0 = fmaf(__shfl(m, k, 64), wp[(k << 6) + lane], x0);
                x1 = fmaf(__shfl(m, k + 1, 64), wp[((k + 1) << 6) + lane], x1);
                x2 = fmaf(__shfl(m, k + 2, 64), wp[((k + 2) << 6) + lane], x2);
                x3 = fmaf(__shfl(m, k + 3, 64), wp[((k + 3) << 6) + lane], x3);
            }
        }
        float xn = (x0 + x1) + (x2 + x3);
        X[o] = xn;
        Xs[o] = dvr * xn;  // premultiplied for next layer's s1
        size_t oo = ob + (size_t)row * 192 + coloff + lane;
        if (bf) ((__hip_bfloat16*)P.out)[oo] = __float2bfloat16(xn);
        else ((float*)P.out)[oo] = xn;
    }
}

__device__ __forceinline__ void ph_stage(const KP& P, int layer, int s,
                                         int gw, int nw, int lane, int bf) {
    switch (s) {
        case 0:  // T1 = A^T (dv o X): layer0 scaled-gather of X, layer1 plain gather of Xs
            if (layer == 0)
                sp_stage<3>(gw, nw, lane,
                            P.cnt_i, P.idx_i, ELL_I, NI, P.Xu, P.T1u, P.dv_u, 0,
                            P.cnt_u, P.idx_u, ELL_U, NU, P.Xi, P.T1i, P.dv_i, 0);
            else
                sp_stage<0>(gw, nw, lane,
                            P.cnt_i, P.idx_i, ELL_I, NI, P.Xsu, P.T1u, 0, 0,
                            P.cnt_u, P.idx_u, ELL_U, NU, P.Xsi, P.T1i, 0, 0);
            break;
        case 1:  // T2 = A T1
            sp_stage<0>(gw, nw, lane,
                        P.cnt_u, P.idx_u, ELL_U, NU, P.T1u, P.TAu, 0, 0,
                        P.cnt_i, P.idx_i, ELL_I, NI, P.T1i, P.TAi, 0, 0);
            break;
        case 2:  // T3 = de2 o (A^T T2)
            sp_stage<1>(gw, nw, lane,
                        P.cnt_i, P.idx_i, ELL_I, NI, P.TAu, P.TBu, P.de2u, 0,
                        P.cnt_u, P.idx_u, ELL_U, NU, P.TAi, P.TBi, P.de2i, 0);
            break;
        case 3:  // T4 = A T3
            sp_stage<0>(gw, nw, lane,
                        P.cnt_u, P.idx_u, ELL_U, NU, P.TBu, P.TAu, 0, 0,
                        P.cnt_i, P.idx_i, ELL_I, NI, P.TBi, P.TAi, 0, 0);
            break;
        case 4:  // S = A^T T4 + de1 o T1
            sp_stage<2>(gw, nw, lane,
                        P.cnt_i, P.idx_i, ELL_I, NI, P.TAu, P.TBu, P.de1u, P.T1u,
                        P.cnt_u, P.idx_u, ELL_U, NU, P.TAi, P.TBi, P.de1i, P.T1i);
            break;
        default:
            sp_final(gw, nw, lane, bf, P, layer ? P.w1 : P.w0, layer ? P.b1 : P.b0,
                     64 + 64 * layer);
            break;
    }
}

__global__ __launch_bounds__(NTHR, 2) void mega(KP P, int phase, int layer) {
    const int t = blockIdx.x * NTHR + threadIdx.x;
    const int stride = gridDim.x * NTHR;
    const int lane = threadIdx.x & 63;
    const int gw = t >> 6;
    const int nw = stride >> 6;
    int bf = (phase >= 1) ? (P.flag[0] == 1u) : 0;
    switch (phase) {
        case 0: ph_zero_detect(P, t, stride); break;
        case 1: ph_fill(P, t, lane, bf); break;
        case 2: ph_spmv1_xinit(P, t, stride, bf); break;
        case 3: ph_spmv2_deg(P, t, stride); break;
        default: ph_stage(P, layer, phase - 4, gw, nw, lane, bf); break;
    }
}

// ---------------- host ----------------

extern "C" void kernel_launch(void* const* d_in, const int* in_sizes, int n_in,
                              void* d_out, int out_size, void* d_ws, size_t ws_size,
                              hipStream_t stream) {
    char* ws = (char*)d_ws;
    size_t off = 0;
    auto alloc = [&](size_t bytes) -> char* {
        char* p = ws + off;
        off = (off + bytes + 255) & ~(size_t)255;
        return p;
    };

    KP P;
    P.Hp = d_in[0]; P.ue = d_in[1]; P.ie = d_in[2];
    P.w0 = d_in[3]; P.b0 = d_in[4]; P.w1 = d_in[5]; P.b1 = d_in[6];
    P.out = d_out;
    P.flag = (u32*)alloc(256);
    P.cnt_u = (int*)alloc(NU * 4);
    P.cnt_i = (int*)alloc(NI * 4);
    P.idx_u = (u16*)alloc((size_t)NU * ELL_U * 2 + 256);
    P.idx_i = (u16*)alloc((size_t)NI * ELL_I * 2 + 256);
    P.a_f = (float*)alloc(NI * 4);
    P.p_f = (float*)alloc(NU * 4);
    P.dv_u = (float*)alloc(NU * 4);
    P.de1u = (float*)alloc(NI * 4);
    P.de2u = (float*)alloc(NI * 4);
    P.dv_i = (float*)alloc(NI * 4);
    P.de1i = (float*)alloc(NU * 4);
    P.de2i = (float*)alloc(NU * 4);
    P.Xu = (float*)alloc((size_t)NU * DE * 4);
    P.Xi = (float*)alloc((size_t)NI * DE * 4);
    P.Xsu = (float*)alloc((size_t)NU * DE * 4);
    P.Xsi = (float*)alloc((size_t)NI * DE * 4);
    P.T1u = (float*)alloc((size_t)NI * DE * 4);
    P.TAu = (float*)alloc((size_t)NU * DE * 4);
    P.TBu = (float*)alloc((size_t)NI * DE * 4);
    P.T1i = (float*)alloc((size_t)NU * DE * 4);
    P.TAi = (float*)alloc((size_t)NI * DE * 4);
    P.TBi = (float*)alloc((size_t)NU * DE * 4);
    (void)ws_size; (void)n_in; (void)in_sizes; (void)out_size;

    auto fire = [&](int phase, int layer, int blocks) {
        hipLaunchKernelGGL(mega, dim3(blocks), dim3(NTHR), 0, stream, P, phase, layer);
    };
    fire(0, 0, 512);    // zero counters + dtype vote
    fire(1, 0, 16384);  // fill ELL (one pass over H, wave-aggregated atomics)
    fire(2, 0, 3072);   // a/p spmv + X fp32 copies + layer-0 out cols
    fire(3, 0, 48);     // b/q spmv + all degree vectors
    for (int L = 0; L < 2; L++)
        for (int s = 0; s < 6; s++)
            fire(4 + s, L, 3072);  // 12 SpMM stages, one row per wave
}

// Round 10
// 421.809 us; speedup vs baseline: 6.9291x; 1.0353x over previous
//
#include <hip/hip_runtime.h>
#include <hip/hip_bf16.h>

typedef unsigned short u16;
typedef unsigned int u32;

#define NU 8192
#define NI 4096
#define DE 64
#define ELL_U 80
#define ELL_I 112
#define EPSF 1e-7f
#define NTHR 256

__device__ __forceinline__ float b2f(__hip_bfloat16 x) { return __bfloat162float(x); }

struct KP {
    const void* Hp; const void* ue; const void* ie;
    const void* w0; const void* b0; const void* w1; const void* b1;
    void* out;
    u32* flag; int* cnt_u; int* cnt_i;
    u16* idx_u; u16* idx_i;
    float* a_f; float* p_f;
    float* dv_u; float* de1u; float* de2u;
    float* dv_i; float* de1i; float* de2i;
    float* Xu; float* Xi; float* Xsu; float* Xsi;
    float* T1u; float* TAu; float* TBu;
    float* T1i; float* TAi; float* TBi;
};

// 8-wide ILP gather with index prefetch (R5's measured-best loop).
// Optional per-source-row scale (SC). Prefetch overreads <=16B past a row's
// live indices; stays inside the 256B-padded workspace arrays.
template <bool SC>
__device__ __forceinline__ float sp_row8(const u16* __restrict__ ip, int n,
                                         const float* __restrict__ src,
                                         const float* __restrict__ scale, int lane) {
    float a0 = 0.f, a1 = 0.f, a2 = 0.f, a3 = 0.f;
    float a4 = 0.f, a5 = 0.f, a6 = 0.f, a7 = 0.f;
    int p = 0;
    if (n >= 8) {
        ushort4 cA = *(const ushort4*)(ip);
        ushort4 cB = *(const ushort4*)(ip + 4);
        while (p + 8 <= n) {
            int c0 = cA.x, c1 = cA.y, c2 = cA.z, c3 = cA.w;
            int c4 = cB.x, c5 = cB.y, c6 = cB.z, c7 = cB.w;
            float g0 = src[((size_t)c0 << 6) + lane];
            float g1 = src[((size_t)c1 << 6) + lane];
            float g2 = src[((size_t)c2 << 6) + lane];
            float g3 = src[((size_t)c3 << 6) + lane];
            float g4 = src[((size_t)c4 << 6) + lane];
            float g5 = src[((size_t)c5 << 6) + lane];
            float g6 = src[((size_t)c6 << 6) + lane];
            float g7 = src[((size_t)c7 << 6) + lane];
            float s0 = 1.f, s1 = 1.f, s2 = 1.f, s3 = 1.f;
            float s4 = 1.f, s5 = 1.f, s6 = 1.f, s7 = 1.f;
            if (SC) {
                s0 = scale[c0]; s1 = scale[c1]; s2 = scale[c2]; s3 = scale[c3];
                s4 = scale[c4]; s5 = scale[c5]; s6 = scale[c6]; s7 = scale[c7];
            }
            p += 8;
            cA = *(const ushort4*)(ip + p);      // prefetch before consuming
            cB = *(const ushort4*)(ip + p + 4);
            if (SC) {
                a0 = fmaf(s0, g0, a0); a1 = fmaf(s1, g1, a1);
                a2 = fmaf(s2, g2, a2); a3 = fmaf(s3, g3, a3);
                a4 = fmaf(s4, g4, a4); a5 = fmaf(s5, g5, a5);
                a6 = fmaf(s6, g6, a6); a7 = fmaf(s7, g7, a7);
            } else {
                a0 += g0; a1 += g1; a2 += g2; a3 += g3;
                a4 += g4; a5 += g5; a6 += g6; a7 += g7;
            }
        }
    }
    if (p + 4 <= n) {
        ushort4 cc = *(const ushort4*)(ip + p);
        float f0 = SC ? scale[cc.x] : 1.f, f1 = SC ? scale[cc.y] : 1.f;
        float f2 = SC ? scale[cc.z] : 1.f, f3 = SC ? scale[cc.w] : 1.f;
        a0 = fmaf(f0, src[((size_t)cc.x << 6) + lane], a0);
        a1 = fmaf(f1, src[((size_t)cc.y << 6) + lane], a1);
        a2 = fmaf(f2, src[((size_t)cc.z << 6) + lane], a2);
        a3 = fmaf(f3, src[((size_t)cc.w << 6) + lane], a3);
        p += 4;
    }
    for (; p < n; p++) {
        int c = ip[p];
        float f = SC ? scale[c] : 1.f;
        a4 = fmaf(f, src[((size_t)c << 6) + lane], a4);
    }
    return ((a0 + a1) + (a2 + a3)) + ((a4 + a5) + (a6 + a7));
}

__device__ __forceinline__ float sv_row_f(const u16* ip, int n, const float* sv) {
    float a0 = 0.f, a1 = 0.f, a2 = 0.f, a3 = 0.f;
    int p = 0;
    for (; p + 4 <= n; p += 4) {
        ushort4 cc = *(const ushort4*)(ip + p);
        a0 += sv[cc.x]; a1 += sv[cc.y]; a2 += sv[cc.z]; a3 += sv[cc.w];
    }
    for (; p < n; p++) a0 += sv[ip[p]];
    return (a0 + a1) + (a2 + a3);
}

__device__ __forceinline__ float sv_row_i(const u16* ip, int n, const int* sv) {
    float a0 = 0.f, a1 = 0.f, a2 = 0.f, a3 = 0.f;
    int p = 0;
    for (; p + 4 <= n; p += 4) {
        ushort4 cc = *(const ushort4*)(ip + p);
        a0 += (float)sv[cc.x]; a1 += (float)sv[cc.y];
        a2 += (float)sv[cc.z]; a3 += (float)sv[cc.w];
    }
    for (; p < n; p++) a0 += (float)sv[ip[p]];
    return (a0 + a1) + (a2 + a3);
}

// ---------------- phases ----------------

// P0: zero counters + dtype vote. H entries are exactly 0.0/1.0: fp32 words
// 0x00000000/0x3F800000 (low u16 always 0); bf16 pairs expose 0x3F80 in the
// low u16 for even-col nnz. Vote via atomicMin (bf16->1, fp32->2): works on
// 0xAA-poisoned flag with no pre-zero; one atomic per wave.
__device__ __forceinline__ void ph_zero_detect(const KP& P, int t, int stride) {
    for (int e = t; e < NU + NI; e += stride) {
        if (e < NU) P.cnt_u[e] = 0;
        else P.cnt_i[e - NU] = 0;
    }
    bool hit = false;
    for (int e = t; e < 131072; e += stride) {
        u32 w = ((const u32*)P.Hp)[e];
        hit |= ((w & 0xFFFFu) == 0x3F80u);
    }
    if (__any(hit ? 1 : 0)) { if ((t & 63) == 0) atomicMin(P.flag, 1u); }
    else                    { if ((t & 63) == 0) atomicMin(P.flag, 2u); }
}

// P1: fill ELL lists, one pass over H. All 64 lanes of a wave cover 512
// consecutive cols of ONE user row -> one cnt_u atomic per wave via prefix
// scan; item-side atomics hit distinct counters (pipeline fine).
__device__ __forceinline__ void ph_fill(const KP& P, int t, int lane, int bf) {
    int q = t;  // 16384x256 grid = one 8-col group per thread
    if (q >= (NU * NI / 8)) return;
    int flat = q << 3;
    int i = flat >> 12;    // user row (wave-uniform: 512 cols per wave)
    int j0 = flat & 4095;  // col base
    u32 words[8];
    if (bf) {
        uint4 v = ((const uint4*)P.Hp)[q];
        u32 p4[4] = {v.x, v.y, v.z, v.w};
#pragma unroll
        for (int k = 0; k < 4; k++) {
            words[2 * k] = p4[k] & 0xFFFFu;
            words[2 * k + 1] = p4[k] >> 16;
        }
    } else {
        uint4 a = ((const uint4*)P.Hp)[2 * q];
        uint4 b = ((const uint4*)P.Hp)[2 * q + 1];
        words[0] = a.x; words[1] = a.y; words[2] = a.z; words[3] = a.w;
        words[4] = b.x; words[5] = b.y; words[6] = b.z; words[7] = b.w;
    }
    u32 m = 0;
#pragma unroll
    for (int e = 0; e < 8; e++)
        if (words[e]) m |= (1u << e);
    int nl = __popc(m);
    int pre = nl;
#pragma unroll
    for (int d = 1; d < 64; d <<= 1) {
        int v = __shfl_up(pre, d, 64);
        if (lane >= d) pre += v;
    }
    int total = __shfl(pre, 63, 64);
    if (total == 0) return;
    int base = 0;
    if (lane == 0) base = atomicAdd(&P.cnt_u[i], total);
    base = __shfl(base, 0, 64);
    int pos = base + (pre - nl);
    if (m) {
#pragma unroll
        for (int e = 0; e < 8; e++) {
            if (m & (1u << e)) {
                int j = j0 + e;
                if (pos < ELL_U) P.idx_u[i * ELL_U + pos] = (u16)j;
                pos++;
                int pi = atomicAdd(&P.cnt_i[j], 1);
                if (pi < ELL_I) P.idx_i[j * ELL_I + pi] = (u16)i;
            }
        }
    }
}

// P2: a = H^T r (item rows), p = H c (user rows)  +  fp32 X copies + layer-0 out
__device__ __forceinline__ void ph_spmv1_xinit(const KP& P, int t, int stride, int bf) {
    for (int r = t; r < NI + NU; r += stride) {
        if (r < NI) {
            int n = min(P.cnt_i[r], ELL_I);
            P.a_f[r] = sv_row_i(P.idx_i + (size_t)r * ELL_I, n, P.cnt_u);
        } else {
            int u = r - NI;
            int n = min(P.cnt_u[u], ELL_U);
            P.p_f[u] = sv_row_i(P.idx_u + (size_t)u * ELL_U, n, P.cnt_i);
        }
    }
    for (int e = t; e < (NU + NI) * DE; e += stride) {
        if (e < NU * DE) {
            int i = e >> 6, l = e & 63;
            float v = bf ? b2f(((const __hip_bfloat16*)P.ue)[e]) : ((const float*)P.ue)[e];
            P.Xu[e] = v;
            size_t o = (size_t)i * 192 + l;
            if (bf) ((__hip_bfloat16*)P.out)[o] = __float2bfloat16(v);
            else ((float*)P.out)[o] = v;
        } else {
            int s = e - NU * DE;
            int i = s >> 6, l = s & 63;
            float v = bf ? b2f(((const __hip_bfloat16*)P.ie)[s]) : ((const float*)P.ie)[s];
            P.Xi[s] = v;
            size_t o = (size_t)(NU + i) * 192 + l;
            if (bf) ((__hip_bfloat16*)P.out)[o] = __float2bfloat16(v);
            else ((float*)P.out)[o] = v;
        }
    }
}

// P3: b = H a (user rows), q = H^T p (item rows) + ALL degree vectors in-thread
__device__ __forceinline__ void ph_spmv2_deg(const KP& P, int t, int stride) {
    for (int r = t; r < NU + NI; r += stride) {
        if (r < NU) {
            int n = min(P.cnt_u[r], ELL_U);
            float b = sv_row_f(P.idx_u + (size_t)r * ELL_U, n, P.a_f);
            float rr = (float)P.cnt_u[r];
            P.dv_u[r] = 1.0f / sqrtf(rr + b + EPSF);
            P.de1i[r] = 1.0f / (rr + EPSF);
            P.de2i[r] = 1.0f / (b + EPSF);
        } else {
            int u = r - NU;
            int n = min(P.cnt_i[u], ELL_I);
            float q = sv_row_f(P.idx_i + (size_t)u * ELL_I, n, P.p_f);
            float cd = (float)P.cnt_i[u];
            P.dv_i[u] = 1.0f / sqrtf(cd + q + EPSF);
            P.de1u[u] = 1.0f / (cd + EPSF);
            P.de2u[u] = 1.0f / (q + EPSF);
        }
    }
}

// MODE 0: dst=acc ; 1: dst=ev[row]*acc ; 2: dst=acc+ev[row]*ax[o] ; 3: scaled-gather, dst=acc
template <int MODE>
__device__ __forceinline__ void sp_stage(int gw, int nw, int lane,
    const int* cA, const u16* iA, int eA, int nA, const float* sA, float* dA,
    const float* vA, const float* xA,
    const int* cB, const u16* iB, int eB, int nB, const float* sB, float* dB,
    const float* vB, const float* xB) {
    for (int r = gw; r < nA + nB; r += nw) {
        bool isA = r < nA;
        const int* c = isA ? cA : cB;
        const u16* idx = isA ? iA : iB;
        int ell = isA ? eA : eB;
        const float* src = isA ? sA : sB;
        float* dst = isA ? dA : dB;
        const float* ev = isA ? vA : vB;
        int row = isA ? r : r - nA;
        int n = min(c[row], ell);
        float acc;
        if (MODE == 3) acc = sp_row8<true>(idx + (size_t)row * ell, n, src, ev, lane);
        else acc = sp_row8<false>(idx + (size_t)row * ell, n, src, 0, lane);
        size_t o = ((size_t)row << 6) + lane;
        if (MODE == 1) {
            dst[o] = ev[row] * acc;
        } else if (MODE == 2) {
            const float* ax = isA ? xA : xB;
            dst[o] = acc + ev[row] * ax[o];
        } else {
            dst[o] = acc;
        }
    }
}

// s6: M = dv*acc + X ; Xnext = M@w + b ; Xs = dv*Xnext ; emit out cols
__device__ __forceinline__ void sp_final(int gw, int nw, int lane, int bf,
    const KP& P, const void* w, const void* bias, int coloff) {
    for (int r = gw; r < NU + NI; r += nw) {
        bool isA = r < NU;
        const int* c = isA ? P.cnt_u : P.cnt_i;
        const u16* idx = isA ? P.idx_u : P.idx_i;
        int ell = isA ? ELL_U : ELL_I;
        const float* src = isA ? P.TBu : P.TBi;
        const float* dvv = isA ? P.dv_u : P.dv_i;
        float* X = isA ? P.Xu : P.Xi;
        float* Xs = isA ? P.Xsu : P.Xsi;
        size_t ob = isA ? (size_t)0 : (size_t)NU * 192;
        int row = isA ? r : r - NU;
        int n = min(c[row], ell);
        float acc = sp_row8<false>(idx + (size_t)row * ell, n, src, 0, lane);
        size_t o = ((size_t)row << 6) + lane;
        float dvr = dvv[row];
        float m = dvr * acc + X[o];
        float x0, x1 = 0.f, x2 = 0.f, x3 = 0.f;
        if (bf) {
            const __hip_bfloat16* __restrict__ wp = (const __hip_bfloat16*)w;
            x0 = b2f(((const __hip_bfloat16*)bias)[lane]);
            for (int k = 0; k < 64; k += 4) {
                x0 = fmaf(__shfl(m, k, 64), b2f(wp[(k << 6) + lane]), x0);
                x1 = fmaf(__shfl(m, k + 1, 64), b2f(wp[((k + 1) << 6) + lane]), x1);
                x2 = fmaf(__shfl(m, k + 2, 64), b2f(wp[((k + 2) << 6) + lane]), x2);
                x3 = fmaf(__shfl(m, k + 3, 64), b2f(wp[((k + 3) << 6) + lane]), x3);
            }
        } else {
            const float* __restrict__ wp = (const float*)w;
            x0 = ((const float*)bias)[lane];
            for (int k = 0; k < 64; k += 4) {
                x0 = fmaf(__shfl(m, k, 64), wp[(k << 6) + lane], x0);
                x1 = fmaf(__shfl(m, k + 1, 64), wp[((k + 1) << 6) + lane], x1);
                x2 = fmaf(__shfl(m, k + 2, 64), wp[((k + 2) << 6) + lane], x2);
                x3 = fmaf(__shfl(m, k + 3, 64), wp[((k + 3) << 6) + lane], x3);
            }
        }
        float xn = (x0 + x1) + (x2 + x3);
        X[o] = xn;
        Xs[o] = dvr * xn;  // premultiplied for next layer's s1
        size_t oo = ob + (size_t)row * 192 + coloff + lane;
        if (bf) ((__hip_bfloat16*)P.out)[oo] = __float2bfloat16(xn);
        else ((float*)P.out)[oo] = xn;
    }
}

__device__ __forceinline__ void ph_stage(const KP& P, int layer, int s,
                                         int gw, int nw, int lane, int bf) {
    switch (s) {
        case 0:  // T1 = A^T (dv o X): layer0 scaled-gather of X, layer1 plain gather of Xs
            if (layer == 0)
                sp_stage<3>(gw, nw, lane,
                            P.cnt_i, P.idx_i, ELL_I, NI, P.Xu, P.T1u, P.dv_u, 0,
                            P.cnt_u, P.idx_u, ELL_U, NU, P.Xi, P.T1i, P.dv_i, 0);
            else
                sp_stage<0>(gw, nw, lane,
                            P.cnt_i, P.idx_i, ELL_I, NI, P.Xsu, P.T1u, 0, 0,
                            P.cnt_u, P.idx_u, ELL_U, NU, P.Xsi, P.T1i, 0, 0);
            break;
        case 1:  // T2 = A T1
            sp_stage<0>(gw, nw, lane,
                        P.cnt_u, P.idx_u, ELL_U, NU, P.T1u, P.TAu, 0, 0,
                        P.cnt_i, P.idx_i, ELL_I, NI, P.T1i, P.TAi, 0, 0);
            break;
        case 2:  // T3 = de2 o (A^T T2)
            sp_stage<1>(gw, nw, lane,
                        P.cnt_i, P.idx_i, ELL_I, NI, P.TAu, P.TBu, P.de2u, 0,
                        P.cnt_u, P.idx_u, ELL_U, NU, P.TAi, P.TBi, P.de2i, 0);
            break;
        case 3:  // T4 = A T3
            sp_stage<0>(gw, nw, lane,
                        P.cnt_u, P.idx_u, ELL_U, NU, P.TBu, P.TAu, 0, 0,
                        P.cnt_i, P.idx_i, ELL_I, NI, P.TBi, P.TAi, 0, 0);
            break;
        case 4:  // S = A^T T4 + de1 o T1
            sp_stage<2>(gw, nw, lane,
                        P.cnt_i, P.idx_i, ELL_I, NI, P.TAu, P.TBu, P.de1u, P.T1u,
                        P.cnt_u, P.idx_u, ELL_U, NU, P.TAi, P.TBi, P.de1i, P.T1i);
            break;
        default:
            sp_final(gw, nw, lane, bf, P, layer ? P.w1 : P.w0, layer ? P.b1 : P.b0,
                     64 + 64 * layer);
            break;
    }
}

__global__ __launch_bounds__(NTHR, 2) void mega(KP P, int phase, int layer) {
    const int t = blockIdx.x * NTHR + threadIdx.x;
    const int stride = gridDim.x * NTHR;
    const int lane = threadIdx.x & 63;
    const int gw = t >> 6;
    const int nw = stride >> 6;
    int bf = (phase >= 1) ? (P.flag[0] == 1u) : 0;
    switch (phase) {
        case 0: ph_zero_detect(P, t, stride); break;
        case 1: ph_fill(P, t, lane, bf); break;
        case 2: ph_spmv1_xinit(P, t, stride, bf); break;
        case 3: ph_spmv2_deg(P, t, stride); break;
        default: ph_stage(P, layer, phase - 4, gw, nw, lane, bf); break;
    }
}

// ---------------- host ----------------

extern "C" void kernel_launch(void* const* d_in, const int* in_sizes, int n_in,
                              void* d_out, int out_size, void* d_ws, size_t ws_size,
                              hipStream_t stream) {
    char* ws = (char*)d_ws;
    size_t off = 0;
    auto alloc = [&](size_t bytes) -> char* {
        char* p = ws + off;
        off = (off + bytes + 255) & ~(size_t)255;
        return p;
    };

    KP P;
    P.Hp = d_in[0]; P.ue = d_in[1]; P.ie = d_in[2];
    P.w0 = d_in[3]; P.b0 = d_in[4]; P.w1 = d_in[5]; P.b1 = d_in[6];
    P.out = d_out;
    P.flag = (u32*)alloc(256);
    P.cnt_u = (int*)alloc(NU * 4);
    P.cnt_i = (int*)alloc(NI * 4);
    P.idx_u = (u16*)alloc((size_t)NU * ELL_U * 2 + 256);
    P.idx_i = (u16*)alloc((size_t)NI * ELL_I * 2 + 256);
    P.a_f = (float*)alloc(NI * 4);
    P.p_f = (float*)alloc(NU * 4);
    P.dv_u = (float*)alloc(NU * 4);
    P.de1u = (float*)alloc(NI * 4);
    P.de2u = (float*)alloc(NI * 4);
    P.dv_i = (float*)alloc(NI * 4);
    P.de1i = (float*)alloc(NU * 4);
    P.de2i = (float*)alloc(NU * 4);
    P.Xu = (float*)alloc((size_t)NU * DE * 4);
    P.Xi = (float*)alloc((size_t)NI * DE * 4);
    P.Xsu = (float*)alloc((size_t)NU * DE * 4);
    P.Xsi = (float*)alloc((size_t)NI * DE * 4);
    P.T1u = (float*)alloc((size_t)NI * DE * 4);
    P.TAu = (float*)alloc((size_t)NU * DE * 4);
    P.TBu = (float*)alloc((size_t)NI * DE * 4);
    P.T1i = (float*)alloc((size_t)NU * DE * 4);
    P.TAi = (float*)alloc((size_t)NI * DE * 4);
    P.TBi = (float*)alloc((size_t)NU * DE * 4);
    (void)ws_size; (void)n_in; (void)in_sizes; (void)out_size;

    auto fire = [&](int phase, int layer, int blocks) {
        hipLaunchKernelGGL(mega, dim3(blocks), dim3(NTHR), 0, stream, P, phase, layer);
    };
    fire(0, 0, 512);    // zero counters + dtype vote
    fire(1, 0, 16384);  // fill ELL (one pass over H, wave-aggregated atomics)
    fire(2, 0, 3072);   // a/p spmv + X fp32 copies + layer-0 out cols
    fire(3, 0, 48);     // b/q spmv + all degree vectors
    for (int L = 0; L < 2; L++)
        for (int s = 0; s < 6; s++)
            fire(4 + s, L, 3072);  // 12 SpMM stages, one row per wave
}